// Round 10
// baseline (390.876 us; speedup 1.0000x reference)
//
#include <hip/hip_runtime.h>
#include <math.h>

// Problem constants
#define N_IMG 128
#define IC 8
#define IH 128
#define IW 128
#define OC 64
#define OH 126
#define OW 126
#define NG 16
#define CPG 4          // channels per group
#define PH 31
#define PW 31
#define GN_EPS 1e-5f
#define CELLS (PH * PW)   // 961

// edge2: 2 consecutive output columns (ow, ow+1) x 4 channels of the 3x3
// conv for one output row. Stats-only edge work (cols 124-125 / rows
// 124-125). ow even (8B-aligned float2 loads). acc pre-init'd with signed
// bias. Weights in LDS [ic][kh][kw][ch], pre-multiplied by sgn(gn_w*scale).
__device__ __forceinline__ void edge2(const float* __restrict__ xb,
                                      const float* wlds_,
                                      int oh, int ow,
                                      float acc[2][CPG]) {
#pragma unroll 1
    for (int ic = 0; ic < IC; ic++) {
        const float* xr = xb + ic * (IH * IW) + oh * IW + ow;
        float xv[3][4];
#pragma unroll
        for (int kh = 0; kh < 3; kh++) {
            float2 a = *(const float2*)(xr + kh * IW);
            float2 b = *(const float2*)(xr + kh * IW + 2);
            xv[kh][0] = a.x; xv[kh][1] = a.y;
            xv[kh][2] = b.x; xv[kh][3] = b.y;
        }
        const float* wk = wlds_ + ic * 36;
#pragma unroll
        for (int kh = 0; kh < 3; kh++) {
            float wr[12];
#pragma unroll
            for (int t = 0; t < 12; t++) wr[t] = wk[kh * 12 + t];
#pragma unroll
            for (int ch = 0; ch < CPG; ch++) {
                float w0 = wr[0 * 4 + ch];
                float w1 = wr[1 * 4 + ch];
                float w2 = wr[2 * 4 + ch];
                acc[0][ch] = fmaf(xv[kh][0], w0,
                             fmaf(xv[kh][1], w1,
                             fmaf(xv[kh][2], w2, acc[0][ch])));
                acc[1][ch] = fmaf(xv[kh][1], w0,
                             fmaf(xv[kh][2], w1,
                             fmaf(xv[kh][3], w2, acc[1][ch])));
            }
        }
    }
}

// load6: 6 x-rows x 6 cols into a register buffer (12 vector loads).
__device__ __forceinline__ void load6(const float* __restrict__ p,
                                      float (&buf)[6][6]) {
#pragma unroll
    for (int rr = 0; rr < 6; rr++) {
        float4 f4 = *(const float4*)(p + rr * IW);
        float2 f2 = *(const float2*)(p + rr * IW + 4);
        buf[rr][0] = f4.x; buf[rr][1] = f4.y;
        buf[rr][2] = f4.z; buf[rr][3] = f4.w;
        buf[rr][4] = f2.x; buf[rr][5] = f2.y;
    }
}

// fma36: one ic's full 3x3 conv contribution for the 4x4xCPG output block.
// 576 FMAs, weights read from LDS (wk = wlds + ic*36).
__device__ __forceinline__ void fma36(const float (&xv)[6][6],
                                      const float* wk,
                                      float (&acc)[4][4][CPG]) {
#pragma unroll
    for (int kh = 0; kh < 3; kh++) {
        float wr[12];
#pragma unroll
        for (int t = 0; t < 12; t++) wr[t] = wk[kh * 12 + t];
#pragma unroll
        for (int ch = 0; ch < CPG; ch++) {
            float w0 = wr[0 * 4 + ch];
            float w1 = wr[1 * 4 + ch];
            float w2 = wr[2 * 4 + ch];
#pragma unroll
            for (int rr = 0; rr < 4; rr++) {
#pragma unroll
                for (int j = 0; j < 4; j++) {
                    acc[rr][j][ch] = fmaf(xv[rr + kh][j],     w0,
                                     fmaf(xv[rr + kh][j + 1], w1,
                                     fmaf(xv[rr + kh][j + 2], w2, acc[rr][j][ch])));
                }
            }
        }
    }
}

// One block per (n, group), XCD-swizzled (verified: FETCH 850MB -> 33MB).
// Single conv pass, proven R3/R8 4-row cell body, single kernel.
//
// BLOCK = 512 THREADS (the round-9 experiment): the session's invariant is
// ~2-3 resident WORKGROUPS/CU regardless of VGPR/LDS/grid (R9's 2x-grid,
// half-work-per-block phase1 ran at the SAME aggregate rate as R8 -- zero
// concurrency gain). If the capped resource is workgroups/CU, doubling
// waves-per-block doubles resident waves (~19/CU vs ~10) and VALUBusy
// should jump 67 -> 80+%. If null, the cap is wave-rate -> pivot to MFMA.
// 961 cells = 2 rounds of 512; edges 250 units (1/thread); 8-wave reduce.
//
// Weights/bias pre-multiplied by sgn(gn_w*scale): pool extreme is a bare
// fmaxf; sum/sumsq per-channel (4 parallel chains).
// out = clamp(rstd*|gn_w*scale|*M + (gn_b - mean*rstd*gn_w)*scale, 0, 1).
__launch_bounds__(512)
__global__ void fused_conv_gn_pool_kernel(const float* __restrict__ x,
                                          const float* __restrict__ conv_w,
                                          const float* __restrict__ conv_b,
                                          const float* __restrict__ gn_w,
                                          const float* __restrict__ gn_b,
                                          const float* __restrict__ scale,
                                          float* __restrict__ out) {
    const int b = blockIdx.x;               // 0..2047 hardware block id
    // XCD-aware swizzle: hw blocks round-robin XCDs by (b % 8); give XCD j
    // the contiguous work range [j*256, (j+1)*256) == images j*16..j*16+15.
    const int wid = ((b & 7) << 8) | (b >> 3);
    const int n = wid >> 4;
    const int g = wid & 15;
    const int tid = threadIdx.x;

    __shared__ float wlds[IC * 3 * 3 * CPG];   // 288 floats, signed
    __shared__ float red[16];                   // 8 waves x {sum, sumsq}
    __shared__ float stats[2];                  // mean, rstd

    for (int t = tid; t < IC * 3 * 3 * CPG; t += 512) {
        int ch = t & 3;
        int r = t >> 2;                        // ic*9 + kh*3 + kw
        int c = g * CPG + ch;
        float sg = (gn_w[c] * scale[c] >= 0.f) ? 1.f : -1.f;
        wlds[t] = conv_w[c * (IC * 9) + r] * sg;
    }
    float biasS[CPG], sgnf[CPG];
#pragma unroll
    for (int ch = 0; ch < CPG; ch++) {
        int c = g * CPG + ch;
        float sg = (gn_w[c] * scale[c] >= 0.f) ? 1.f : -1.f;
        sgnf[ch] = sg;
        biasS[ch] = conv_b[c] * sg;
    }
    __syncthreads();

    const float* xb = x + (size_t)n * (IC * IH * IW);
    const int CS = IH * IW;                    // channel stride

    float s_ch[CPG];                 // per-channel signed partial sums
    float ss_ch[CPG];                // per-channel sum of squares
#pragma unroll
    for (int ch = 0; ch < CPG; ch++) { s_ch[ch] = 0.f; ss_ch[ch] = 0.f; }
    float pm[2][CPG];                // pooled signed max per owned cell
#pragma unroll
    for (int r = 0; r < 2; r++)
#pragma unroll
        for (int ch = 0; ch < CPG; ch++) pm[r][ch] = -INFINITY;

    // ---- Main: pool region (conv rows/cols 0..123), 2 rounds of 512 ----
#pragma unroll 1
    for (int r = 0; r < 2; r++) {
        int cell = r * 512 + tid;
        if (cell < CELLS) {
            int ph = cell / PW;
            int pw = cell - ph * PW;
            const int r0 = 4 * ph;             // conv rows r0..r0+3
            const float* xcell = xb + r0 * IW + 4 * pw;

            float acc[4][4][CPG];              // [row][col][ch]
#pragma unroll
            for (int rr = 0; rr < 4; rr++)
#pragma unroll
                for (int j = 0; j < 4; j++)
#pragma unroll
                    for (int ch = 0; ch < CPG; ch++) acc[rr][j][ch] = biasS[ch];

#pragma unroll 1
            for (int ic = 0; ic < IC; ic++) {
                float xv[6][6];
                load6(xcell + ic * CS, xv);
                fma36(xv, wlds + ic * 36, acc);
            }

            // fold into stats + pool extremes (signed domain)
#pragma unroll
            for (int rr = 0; rr < 4; rr++)
#pragma unroll
                for (int j = 0; j < 4; j++)
#pragma unroll
                    for (int ch = 0; ch < CPG; ch++) {
                        float v = acc[rr][j][ch];
                        s_ch[ch] += v;
                        ss_ch[ch] = fmaf(v, v, ss_ch[ch]);
                        pm[r][ch] = fmaxf(pm[r][ch], v);
                    }
        }
    }

    // ---- Edges (stats only): 250 fine-grained units, 1/thread ----
    //   u<124: right edge row u, cols 124-125
    //   else u2=u-124: oh=124+(u2>=63), col pair (u2 mod 63)*2
    if (tid < 250) {
        int oh, ow;
        if (tid < 124) {
            oh = tid; ow = 124;
        } else {
            int u2 = tid - 124;
            int hi = (u2 >= 63) ? 1 : 0;
            oh = 124 + hi;
            ow = (u2 - 63 * hi) * 2;
        }
        float acc[2][CPG];
#pragma unroll
        for (int j = 0; j < 2; j++)
#pragma unroll
            for (int ch = 0; ch < CPG; ch++) acc[j][ch] = biasS[ch];
        edge2(xb, wlds, oh, ow, acc);
#pragma unroll
        for (int j = 0; j < 2; j++)
#pragma unroll
            for (int ch = 0; ch < CPG; ch++) {
                float v = acc[j][ch];
                s_ch[ch] += v;
                ss_ch[ch] = fmaf(v, v, ss_ch[ch]);
            }
    }

    // ---- Block reduction for GN stats (restore per-channel sign) ----
    float s = sgnf[0] * s_ch[0] + sgnf[1] * s_ch[1]
            + sgnf[2] * s_ch[2] + sgnf[3] * s_ch[3];
    float ss = ss_ch[0] + ss_ch[1] + ss_ch[2] + ss_ch[3];
#pragma unroll
    for (int off = 32; off > 0; off >>= 1) {
        s  += __shfl_down(s, off, 64);
        ss += __shfl_down(ss, off, 64);
    }
    int wave = tid >> 6;                       // 0..7
    if ((tid & 63) == 0) { red[wave] = s; red[8 + wave] = ss; }
    __syncthreads();
    if (tid == 0) {
        float S = 0.f, SS = 0.f;
#pragma unroll
        for (int w = 0; w < 8; w++) { S += red[w]; SS += red[8 + w]; }
        const float inv_count = 1.f / (float)(CPG * OH * OW);
        float mean = S * inv_count;
        float var = SS * inv_count - mean * mean;
        if (var < 0.f) var = 0.f;
        stats[0] = mean;
        stats[1] = rsqrtf(var + GN_EPS);
    }
    __syncthreads();
    const float mean = stats[0];
    const float rstd = stats[1];

    // Fused affine for the pooled extreme: out = a2*M + b2  (a2 >= 0,
    // M is the signed-domain max, equal to max over window of sgn*v)
    float a2[CPG], b2[CPG];
#pragma unroll
    for (int ch = 0; ch < CPG; ch++) {
        int c = g * CPG + ch;
        float gw = gn_w[c], sc = scale[c];
        a2[ch] = rstd * fabsf(gw * sc);
        b2[ch] = (gn_b[c] - mean * rstd * gw) * sc;
    }

    // ---- Write pooled, clamped output ----
#pragma unroll 1
    for (int r = 0; r < 2; r++) {
        int cell = r * 512 + tid;
        if (cell < CELLS) {
            int ph = cell / PW;
            int pw = cell - ph * PW;
#pragma unroll
            for (int ch = 0; ch < CPG; ch++) {
                int c = g * CPG + ch;
                float v = fmaf(a2[ch], pm[r][ch], b2[ch]);
                v = fminf(fmaxf(v, 0.f), 1.f);
                out[(((size_t)n * OC + c) * PH + ph) * PW + pw] = v;
            }
        }
    }
}

extern "C" void kernel_launch(void* const* d_in, const int* in_sizes, int n_in,
                              void* d_out, int out_size, void* d_ws, size_t ws_size,
                              hipStream_t stream) {
    const float* x      = (const float*)d_in[0];
    const float* conv_w = (const float*)d_in[1];
    const float* conv_b = (const float*)d_in[2];
    const float* gn_w   = (const float*)d_in[3];
    const float* gn_b   = (const float*)d_in[4];
    const float* scale  = (const float*)d_in[5];
    float* out = (float*)d_out;

    dim3 grid(N_IMG * NG);   // one block per (n, group), XCD-swizzled in-kernel
    dim3 block(512);
    hipLaunchKernelGGL(fused_conv_gn_pool_kernel, grid, block, 0, stream,
                       x, conv_w, conv_b, gn_w, gn_b, scale, out);
}

// Round 11
// 335.742 us; speedup vs baseline: 1.1642x; 1.1642x over previous
//
#include <hip/hip_runtime.h>
#include <math.h>

// Problem constants
#define N_IMG 128
#define IC 8
#define IH 128
#define IW 128
#define OC 64
#define OH 126
#define OW 126
#define NG 16
#define CPG 4          // channels per group
#define PH 31
#define PW 31
#define GN_EPS 1e-5f

typedef float f32x2 __attribute__((ext_vector_type(2)));

// Packed dual-FP32 FMA: d = a*b + c per 32-bit half (VOP3P, gfx90a+).
// Bit-identical to two scalar fmaf. No memory side effects -> freely
// schedulable by the compiler (deps carried through operands).
__device__ __forceinline__ f32x2 pk_fma(f32x2 a, f32x2 b, f32x2 c) {
    f32x2 d;
    asm("v_pk_fma_f32 %0, %1, %2, %3" : "=v"(d) : "v"(a), "v"(b), "v"(c));
    return d;
}

// edge2: 2 consecutive output columns (ow, ow+1) x 4 channels of the 3x3
// conv for one output row. Stats-only edge work (cols 124-125 / rows
// 124-125). ow even (8B-aligned float2 loads). acc pre-init'd with signed
// bias. Weights in LDS [ic][kh][kw][ch], pre-multiplied by sgn(gn_w*scale).
__device__ __forceinline__ void edge2(const float* __restrict__ xb,
                                      const float* wlds_,
                                      int oh, int ow,
                                      float acc[2][CPG]) {
#pragma unroll 1
    for (int ic = 0; ic < IC; ic++) {
        const float* xr = xb + ic * (IH * IW) + oh * IW + ow;
        float xv[3][4];
#pragma unroll
        for (int kh = 0; kh < 3; kh++) {
            float2 a = *(const float2*)(xr + kh * IW);
            float2 b = *(const float2*)(xr + kh * IW + 2);
            xv[kh][0] = a.x; xv[kh][1] = a.y;
            xv[kh][2] = b.x; xv[kh][3] = b.y;
        }
        const float* wk = wlds_ + ic * 36;
#pragma unroll
        for (int kh = 0; kh < 3; kh++) {
            float wr[12];
#pragma unroll
            for (int t = 0; t < 12; t++) wr[t] = wk[kh * 12 + t];
#pragma unroll
            for (int ch = 0; ch < CPG; ch++) {
                float w0 = wr[0 * 4 + ch];
                float w1 = wr[1 * 4 + ch];
                float w2 = wr[2 * 4 + ch];
                acc[0][ch] = fmaf(xv[kh][0], w0,
                             fmaf(xv[kh][1], w1,
                             fmaf(xv[kh][2], w2, acc[0][ch])));
                acc[1][ch] = fmaf(xv[kh][1], w0,
                             fmaf(xv[kh][2], w1,
                             fmaf(xv[kh][3], w2, acc[1][ch])));
            }
        }
    }
}

// One block per (n, group), XCD-swizzled (verified: FETCH 850MB -> 33MB).
// Proven R3/R8 structure: 256 threads, 4 cell-rounds, simple ic loop
// (ILP fences/dbuf and TLP splits all measured neutral-to-negative,
// R4-R10). NEW: the conv core uses v_pk_fma_f32 -- channels pair naturally
// (weights ch-adjacent in LDS -> 8B pairs; acc pairs (ch0,ch1),(ch2,ch3);
// x broadcast {x,x}, 36 dups/ic amortized over 288 pk). 576 scalar FMA ->
// 288 pk + 36 dup = ~45% fewer VALU instructions, bit-identical results.
// This is the decisive fp32-rate experiment: full-rate packed -> ~1.5x;
// rate-neutral -> unchanged, pivot to MFMA.
//
// amdgpu_waves_per_eu(2,4) serves two proven purposes: (a) 256-VGPR budget
// so the wider live set (~190) doesn't spill (R5/R6 lesson); (b) prevents
// promote-alloca from moving private arrays to LDS (R9/R10: LDS 9.7-17.9KB
// + 753K bank conflicts when the attribute was dropped).
//
// Weights/bias pre-multiplied by sgn(gn_w*scale): pool extreme is a bare
// fmaxf; sum/sumsq per-channel (parallel chains).
// out = clamp(rstd*|gn_w*scale|*M + (gn_b - mean*rstd*gn_w)*scale, 0, 1).
__attribute__((amdgpu_waves_per_eu(2, 4)))
__launch_bounds__(256)
__global__ void fused_conv_gn_pool_kernel(const float* __restrict__ x,
                                          const float* __restrict__ conv_w,
                                          const float* __restrict__ conv_b,
                                          const float* __restrict__ gn_w,
                                          const float* __restrict__ gn_b,
                                          const float* __restrict__ scale,
                                          float* __restrict__ out) {
    const int b = blockIdx.x;               // 0..2047 hardware block id
    // XCD-aware swizzle: hw blocks round-robin XCDs by (b % 8); give XCD j
    // the contiguous work range [j*256, (j+1)*256) == images j*16..j*16+15.
    const int wid = ((b & 7) << 8) | (b >> 3);
    const int n = wid >> 4;
    const int g = wid & 15;
    const int tid = threadIdx.x;

    __shared__ __align__(16) float wlds[IC * 3 * 3 * CPG]; // [ic][kh][kw][ch], signed
    __shared__ float red[8];                    // 4 waves x {sum, sumsq}
    __shared__ float stats[2];                  // mean, rstd

    for (int t = tid; t < IC * 3 * 3 * CPG; t += 256) {
        int ch = t & 3;
        int r = t >> 2;                        // ic*9 + kh*3 + kw
        int c = g * CPG + ch;
        float sg = (gn_w[c] * scale[c] >= 0.f) ? 1.f : -1.f;
        wlds[t] = conv_w[c * (IC * 9) + r] * sg;
    }
    float biasS[CPG], sgnf[CPG];
#pragma unroll
    for (int ch = 0; ch < CPG; ch++) {
        int c = g * CPG + ch;
        float sg = (gn_w[c] * scale[c] >= 0.f) ? 1.f : -1.f;
        sgnf[ch] = sg;
        biasS[ch] = conv_b[c] * sg;
    }
    __syncthreads();

    const float* xb = x + (size_t)n * (IC * IH * IW);
    const int CS = IH * IW;                    // channel stride

    float s_ch[CPG];                 // per-channel signed partial sums
    float ss_ch[CPG];                // per-channel sum of squares
#pragma unroll
    for (int ch = 0; ch < CPG; ch++) { s_ch[ch] = 0.f; ss_ch[ch] = 0.f; }
    float pm[4][CPG];                // pooled signed max per owned cell
#pragma unroll
    for (int ci = 0; ci < 4; ci++)
#pragma unroll
        for (int ch = 0; ch < CPG; ch++) pm[ci][ch] = -INFINITY;

    // ---- Main: pool region (conv rows/cols 0..123), one pass ----
#pragma unroll 1
    for (int ci = 0; ci < 4; ci++) {
        int cell = tid + ci * 256;
        if (cell < PH * PW) {
            int ph = cell / PW;
            int pw = cell - ph * PW;
            const int r0 = 4 * ph;             // conv rows r0..r0+3
            const float* xcell = xb + r0 * IW + 4 * pw;

            f32x2 accp[4][4][2];               // [row][col][chpair]
            f32x2 biasP0 = {biasS[0], biasS[1]};
            f32x2 biasP1 = {biasS[2], biasS[3]};
#pragma unroll
            for (int rr = 0; rr < 4; rr++)
#pragma unroll
                for (int j = 0; j < 4; j++) {
                    accp[rr][j][0] = biasP0;
                    accp[rr][j][1] = biasP1;
                }

#pragma unroll 1
            for (int ic = 0; ic < IC; ic++) {
                const float* xr = xcell + ic * CS;
                // 6 rows x 6 cols, broadcast into {x,x} pairs for pk_fma
                f32x2 xd[6][6];
#pragma unroll
                for (int rr = 0; rr < 6; rr++) {
                    float4 f4 = *(const float4*)(xr + rr * IW);
                    float2 f2 = *(const float2*)(xr + rr * IW + 4);
                    xd[rr][0] = {f4.x, f4.x}; xd[rr][1] = {f4.y, f4.y};
                    xd[rr][2] = {f4.z, f4.z}; xd[rr][3] = {f4.w, f4.w};
                    xd[rr][4] = {f2.x, f2.x}; xd[rr][5] = {f2.y, f2.y};
                }
                const float* wk = wlds + ic * 36;
#pragma unroll
                for (int kh = 0; kh < 3; kh++) {
                    // 6 weight pairs: [kw0p0 kw0p1 kw1p0 kw1p1 kw2p0 kw2p1]
                    const f32x2* wkp = (const f32x2*)(wk + kh * 12);
                    f32x2 w[6];
#pragma unroll
                    for (int t = 0; t < 6; t++) w[t] = wkp[t];
#pragma unroll
                    for (int kw = 0; kw < 3; kw++)
#pragma unroll
                        for (int rr = 0; rr < 4; rr++)
#pragma unroll
                            for (int j = 0; j < 4; j++) {
                                f32x2 xx = xd[rr + kh][j + kw];
                                accp[rr][j][0] = pk_fma(xx, w[kw * 2],     accp[rr][j][0]);
                                accp[rr][j][1] = pk_fma(xx, w[kw * 2 + 1], accp[rr][j][1]);
                            }
                }
            }

            // fold into stats + pool extremes (signed domain)
#pragma unroll
            for (int rr = 0; rr < 4; rr++)
#pragma unroll
                for (int j = 0; j < 4; j++) {
                    f32x2 v01 = accp[rr][j][0];
                    f32x2 v23 = accp[rr][j][1];
                    s_ch[0] += v01.x;  ss_ch[0] = fmaf(v01.x, v01.x, ss_ch[0]);
                    pm[ci][0] = fmaxf(pm[ci][0], v01.x);
                    s_ch[1] += v01.y;  ss_ch[1] = fmaf(v01.y, v01.y, ss_ch[1]);
                    pm[ci][1] = fmaxf(pm[ci][1], v01.y);
                    s_ch[2] += v23.x;  ss_ch[2] = fmaf(v23.x, v23.x, ss_ch[2]);
                    pm[ci][2] = fmaxf(pm[ci][2], v23.x);
                    s_ch[3] += v23.y;  ss_ch[3] = fmaf(v23.y, v23.y, ss_ch[3]);
                    pm[ci][3] = fmaxf(pm[ci][3], v23.y);
                }
        }
    }

    // ---- Edges (stats only): 250 fine-grained units, 1/thread ----
    //   u<124: right edge row u, cols 124-125
    //   else u2=u-124: oh=124+(u2>=63), col pair (u2 mod 63)*2
    if (tid < 250) {
        int oh, ow;
        if (tid < 124) {
            oh = tid; ow = 124;
        } else {
            int u2 = tid - 124;
            int hi = (u2 >= 63) ? 1 : 0;
            oh = 124 + hi;
            ow = (u2 - 63 * hi) * 2;
        }
        float acc[2][CPG];
#pragma unroll
        for (int j = 0; j < 2; j++)
#pragma unroll
            for (int ch = 0; ch < CPG; ch++) acc[j][ch] = biasS[ch];
        edge2(xb, wlds, oh, ow, acc);
#pragma unroll
        for (int j = 0; j < 2; j++)
#pragma unroll
            for (int ch = 0; ch < CPG; ch++) {
                float v = acc[j][ch];
                s_ch[ch] += v;
                ss_ch[ch] = fmaf(v, v, ss_ch[ch]);
            }
    }

    // ---- Block reduction for GN stats (restore per-channel sign) ----
    float s = sgnf[0] * s_ch[0] + sgnf[1] * s_ch[1]
            + sgnf[2] * s_ch[2] + sgnf[3] * s_ch[3];
    float ss = ss_ch[0] + ss_ch[1] + ss_ch[2] + ss_ch[3];
#pragma unroll
    for (int off = 32; off > 0; off >>= 1) {
        s  += __shfl_down(s, off, 64);
        ss += __shfl_down(ss, off, 64);
    }
    int wave = tid >> 6;
    if ((tid & 63) == 0) { red[wave] = s; red[4 + wave] = ss; }
    __syncthreads();
    if (tid == 0) {
        float S  = red[0] + red[1] + red[2] + red[3];
        float SS = red[4] + red[5] + red[6] + red[7];
        const float inv_count = 1.f / (float)(CPG * OH * OW);
        float mean = S * inv_count;
        float var = SS * inv_count - mean * mean;
        if (var < 0.f) var = 0.f;
        stats[0] = mean;
        stats[1] = rsqrtf(var + GN_EPS);
    }
    __syncthreads();
    const float mean = stats[0];
    const float rstd = stats[1];

    // Fused affine for the pooled extreme: out = a2*M + b2  (a2 >= 0,
    // M is the signed-domain max, equal to max over window of sgn*v)
    float a2[CPG], b2[CPG];
#pragma unroll
    for (int ch = 0; ch < CPG; ch++) {
        int c = g * CPG + ch;
        float gw = gn_w[c], sc = scale[c];
        a2[ch] = rstd * fabsf(gw * sc);
        b2[ch] = (gn_b[c] - mean * rstd * gw) * sc;
    }

    // ---- Write pooled, clamped output ----
#pragma unroll
    for (int ci = 0; ci < 4; ci++) {
        int cell = tid + ci * 256;
        if (cell < PH * PW) {
            int ph = cell / PW;
            int pw = cell - ph * PW;
#pragma unroll
            for (int ch = 0; ch < CPG; ch++) {
                int c = g * CPG + ch;
                float v = fmaf(a2[ch], pm[ci][ch], b2[ch]);
                v = fminf(fmaxf(v, 0.f), 1.f);
                out[(((size_t)n * OC + c) * PH + ph) * PW + pw] = v;
            }
        }
    }
}

extern "C" void kernel_launch(void* const* d_in, const int* in_sizes, int n_in,
                              void* d_out, int out_size, void* d_ws, size_t ws_size,
                              hipStream_t stream) {
    const float* x      = (const float*)d_in[0];
    const float* conv_w = (const float*)d_in[1];
    const float* conv_b = (const float*)d_in[2];
    const float* gn_w   = (const float*)d_in[3];
    const float* gn_b   = (const float*)d_in[4];
    const float* scale  = (const float*)d_in[5];
    float* out = (float*)d_out;

    dim3 grid(N_IMG * NG);   // one block per (n, group), XCD-swizzled in-kernel
    dim3 block(256);
    hipLaunchKernelGGL(fused_conv_gn_pool_kernel, grid, block, 0, stream,
                       x, conv_w, conv_b, gn_w, gn_b, scale, out);
}

// Round 13
// 328.920 us; speedup vs baseline: 1.1884x; 1.0207x over previous
//
#include <hip/hip_runtime.h>
#include <math.h>

// Problem constants
#define N_IMG 128
#define IC 8
#define IH 128
#define IW 128
#define OC 64
#define NG 16
#define PH 31
#define PW 31
#define GN_EPS 1e-5f
#define CSTR (IH * IW)      // channel stride in x
#define NBAND 4             // pool-row bands per image

typedef float f32x4 __attribute__((ext_vector_type(4)));
typedef short s16x8 __attribute__((ext_vector_type(8)));
typedef int   i32x4 __attribute__((ext_vector_type(4)));

// v_cvt_pk_bf16_f32: pack two f32 into one dword of 2 bf16 (RNE). No builtin
// on gfx950 -- inline asm per guide T12 (HW-verified pattern, m240).
__device__ __forceinline__ unsigned cvt_pk_bf16(float a, float b) {
    unsigned r;
    asm("v_cvt_pk_bf16_f32 %0, %1, %2" : "=v"(r) : "v"(a), "v"(b));
    return r;
}
__device__ __forceinline__ float bf16lo_f(unsigned p) { return __uint_as_float(p << 16); }
__device__ __forceinline__ float bf16hi_f(unsigned p) { return __uint_as_float(p & 0xFFFF0000u); }

__device__ __forceinline__ s16x8 mk_frag(unsigned a, unsigned b, unsigned c, unsigned d) {
    union { i32x4 i; s16x8 s; } u;
    u.i = (i32x4){(int)a, (int)b, (int)c, (int)d};
    return u.s;
}

// split 8 f32 (k-elements e0..e7) into hi/lo bf16 fragments.
// hi = rne_bf16(v); lo = rne_bf16(v - f32(hi)) -> v ~= hi + lo to ~2^-17 rel.
__device__ __forceinline__ void split8(const float v[8], s16x8* hi, s16x8* lo) {
    unsigned h[4], l[4];
#pragma unroll
    for (int e = 0; e < 4; e++) {
        float a = v[2 * e], b = v[2 * e + 1];
        unsigned hp = cvt_pk_bf16(a, b);
        float ra = a - bf16lo_f(hp);
        float rb = b - bf16hi_f(hp);
        h[e] = hp;
        l[e] = cvt_pk_bf16(ra, rb);
    }
    *hi = mk_frag(h[0], h[1], h[2], h[3]);
    *lo = mk_frag(l[0], l[1], l[2], l[3]);
}

// PHASE 1 -- MFMA implicit-GEMM conv + pool-max + partial GN stats.
// (Resubmission of R12: the bench failed at container level, not kernel
// level; audit found no OOB/hang/ISA hazard -- see round notes.)
//
// GEMM view per MFMA (16x16x32 bf16): A = signed weights, M=16 channels;
// B = im2col patches, N=16 positions; K = ic*12 + kh*4 + kw (96 padded,
// kw=3 weight = 0 so each lane k-quad = 4 CONSECUTIVE x columns).
// Lane maps: A row / B col = lane&15; k = 32*s + 16*h + (lane>>4)*4 + e
// (any bijective k-map is valid as long as A and B agree -- MFMA pairs
// same-slot elements); D (m89 HW-verified): col(pos)=lane&15,
// row(ch)=(lane>>4)*4+reg.
// One MFMA's 16 positions = one 4x4 POOL WINDOW; one lane's 4 acc regs =
// one GN GROUP (channels 4a..4a+3). Pool max / stats = shfl_xor(1,2,4,8)
// over the 16-lane position group. Split-bf16: D += Ah*Bh + Ah*Bl + Al*Bh.
//
// Block = (n, band of 8 pool rows): 512 blocks x 256 thr. Each wave: all 64
// channels (4 A-sets of 16) for its strided share of cells. Edge stats
// (conv cols 124-125 all rows; rows 124-125 cols 0..123) via masked MFMA
// cells. Partial sums -> ws; raw pooled signed-max -> out; phase 2 applies
// the affine in place (proven R9 pattern).
__attribute__((amdgpu_waves_per_eu(2, 4)))
__launch_bounds__(256)
__global__ void conv_pool_mfma_phase1(const float* __restrict__ x,
                                      const float* __restrict__ conv_w,
                                      const float* __restrict__ conv_b,
                                      const float* __restrict__ gn_w,
                                      const float* __restrict__ gn_b,
                                      const float* __restrict__ scale,
                                      float* __restrict__ out,
                                      float* __restrict__ ws) {
    const int b = blockIdx.x;                  // 0..511
    const int wid = ((b & 7) << 6) | (b >> 3); // XCD swizzle (512 = 8x64, bijective)
    const int n = wid >> 2;
    const int band = wid & 3;
    const int tid = threadIdx.x;
    const int lane = tid & 63;
    const int wave = tid >> 6;
    const int p15 = lane & 15;                 // A-row / B-col / D-col index
    const int lg = lane >> 4;                  // k-quad selector / D row group

    __shared__ float gsum[4][NG][2];           // per-wave group partials

    const float* xn = x + (size_t)n * (IC * CSTR);

    // ---- per-lane k-quad decode: sh = s*2+half -> (ic, kh) ----
    int icA[6], khA[6], rowoffA[6];
#pragma unroll
    for (int sh = 0; sh < 6; sh++) {
        int s = sh >> 1, h = sh & 1;
        int k0 = 32 * s + 16 * h + 4 * lg;     // multiple of 4
        int ic = k0 / 12;
        int kk = k0 - 12 * ic;                 // 0,4,8
        int kh = kk >> 2;
        icA[sh] = ic; khA[sh] = kh;
        rowoffA[sh] = ic * CSTR + kh * IW;
    }

    // ---- A fragments: signed weights, hi/lo split, all 4 ch-sets ----
    s16x8 Ah[4][3], Al[4][3];
#pragma unroll
    for (int q = 0; q < 4; q++) {
        int c = q * 16 + p15;
        float sg = (gn_w[c] * scale[c] >= 0.f) ? 1.f : -1.f;
#pragma unroll
        for (int s = 0; s < 3; s++) {
            float wf[8];
#pragma unroll
            for (int h = 0; h < 2; h++) {
                int sh = s * 2 + h;
                int ic = icA[sh], kh = khA[sh];
#pragma unroll
                for (int kw = 0; kw < 4; kw++)
                    wf[h * 4 + kw] = (kw < 3)
                        ? conv_w[c * (IC * 9) + ic * 9 + kh * 3 + kw] * sg
                        : 0.f;
            }
            split8(wf, &Ah[q][s], &Al[q][s]);
        }
    }

    // ---- bias/sign for the ACC layout channels (q*16 + lg*4 + reg) ----
    float bias4[4][4], sgn4[4][4];
#pragma unroll
    for (int q = 0; q < 4; q++)
#pragma unroll
        for (int r = 0; r < 4; r++) {
            int c = q * 16 + 4 * lg + r;
            float sg = (gn_w[c] * scale[c] >= 0.f) ? 1.f : -1.f;
            sgn4[q][r] = sg;
            bias4[q][r] = conv_b[c] * sg;
        }

    float sA[4], ssA[4];
#pragma unroll
    for (int q = 0; q < 4; q++) { sA[q] = 0.f; ssA[q] = 0.f; }

    // ================= main cells (pool windows) =================
    const int nc = (band < 3) ? 8 * PW : 7 * PW;   // 248 / 217
    const int phb = band * 8;
    const int pi = p15 >> 2, pj = p15 & 3;         // pos in 4x4 window

#pragma unroll 1
    for (int cell = wave; cell < nc; cell += 4) {
        int lph = cell / 31;
        int pwc = cell - lph * 31;
        int ph = phb + lph;
        int posoff = (4 * ph + pi) * IW + 4 * pwc + pj;

        f32x4 acc[4];
#pragma unroll
        for (int q = 0; q < 4; q++)
            acc[q] = (f32x4){bias4[q][0], bias4[q][1], bias4[q][2], bias4[q][3]};

#pragma unroll
        for (int s = 0; s < 3; s++) {
            float bv[8];
#pragma unroll
            for (int h = 0; h < 2; h++) {
                const float* p = xn + rowoffA[s * 2 + h] + posoff;
                bv[h * 4 + 0] = p[0]; bv[h * 4 + 1] = p[1];
                bv[h * 4 + 2] = p[2]; bv[h * 4 + 3] = p[3];
            }
            s16x8 Bh, Bl;
            split8(bv, &Bh, &Bl);
#pragma unroll
            for (int q = 0; q < 4; q++) {
                acc[q] = __builtin_amdgcn_mfma_f32_16x16x32_bf16(Ah[q][s], Bh, acc[q], 0, 0, 0);
                acc[q] = __builtin_amdgcn_mfma_f32_16x16x32_bf16(Ah[q][s], Bl, acc[q], 0, 0, 0);
                acc[q] = __builtin_amdgcn_mfma_f32_16x16x32_bf16(Al[q][s], Bh, acc[q], 0, 0, 0);
            }
        }

        // fold: stats (group-pre-summed) + pooled max over the 16 positions
#pragma unroll
        for (int q = 0; q < 4; q++) {
            float m0 = acc[q][0], m1 = acc[q][1], m2 = acc[q][2], m3 = acc[q][3];
            float sp = sgn4[q][0] * m0 + sgn4[q][1] * m1
                     + sgn4[q][2] * m2 + sgn4[q][3] * m3;
            float sq = m0 * m0 + m1 * m1 + m2 * m2 + m3 * m3;
#pragma unroll
            for (int o = 1; o < 16; o <<= 1) {
                sp += __shfl_xor(sp, o, 64);
                sq += __shfl_xor(sq, o, 64);
                m0 = fmaxf(m0, __shfl_xor(m0, o, 64));
                m1 = fmaxf(m1, __shfl_xor(m1, o, 64));
                m2 = fmaxf(m2, __shfl_xor(m2, o, 64));
                m3 = fmaxf(m3, __shfl_xor(m3, o, 64));
            }
            sA[q] += sp; ssA[q] += sq;
            if (p15 == 0) {
                int c = q * 16 + 4 * lg;
                size_t ob = (((size_t)n * OC + c) * PH + ph) * PW + pwc;
                out[ob] = m0;
                out[ob + PH * PW] = m1;
                out[ob + 2 * PH * PW] = m2;
                out[ob + 3 * PH * PW] = m3;
            }
        }
    }

    // ================= edge cells (stats only, masked) =================
    // 32 per image: eb<16 -> right edge (cols 124-125, 8 rows x 2 cols per
    // cell); eb>=16 -> bottom rows 124-125 (2 rows x 8 cols per cell).
#pragma unroll 1
    for (int t = 2 * wave; t < 2 * wave + 2; t++) {
        int eb = band * 8 + t;
        int posrow, poscol, valid;
        if (eb < 16) {
            posrow = 8 * eb + (p15 >> 1);
            poscol = 124 + (p15 & 1);
            valid = (posrow <= 125);
        } else {
            posrow = 124 + (p15 >> 3);
            poscol = 8 * (eb - 16) + (p15 & 7);
            valid = (poscol <= 123);
        }

        f32x4 acc[4];
#pragma unroll
        for (int q = 0; q < 4; q++)
            acc[q] = (f32x4){bias4[q][0], bias4[q][1], bias4[q][2], bias4[q][3]};

#pragma unroll
        for (int s = 0; s < 3; s++) {
            float bv[8];
#pragma unroll
            for (int h = 0; h < 2; h++) {
                int sh = s * 2 + h;
                int xr = posrow + khA[sh]; if (xr > 127) xr = 127;
                const float* p = xn + icA[sh] * CSTR + xr * IW;
                int c0 = poscol;
                int c1 = c0 + 1; if (c1 > 127) c1 = 127;
                int c2 = c0 + 2; if (c2 > 127) c2 = 127;
                int c3 = c0 + 3; if (c3 > 127) c3 = 127;
                bv[h * 4 + 0] = p[c0]; bv[h * 4 + 1] = p[c1];
                bv[h * 4 + 2] = p[c2]; bv[h * 4 + 3] = p[c3];
            }
            s16x8 Bh, Bl;
            split8(bv, &Bh, &Bl);
#pragma unroll
            for (int q = 0; q < 4; q++) {
                acc[q] = __builtin_amdgcn_mfma_f32_16x16x32_bf16(Ah[q][s], Bh, acc[q], 0, 0, 0);
                acc[q] = __builtin_amdgcn_mfma_f32_16x16x32_bf16(Ah[q][s], Bl, acc[q], 0, 0, 0);
                acc[q] = __builtin_amdgcn_mfma_f32_16x16x32_bf16(Al[q][s], Bh, acc[q], 0, 0, 0);
            }
        }

        float vmask = valid ? 1.f : 0.f;
#pragma unroll
        for (int q = 0; q < 4; q++) {
            float m0 = acc[q][0] * vmask, m1 = acc[q][1] * vmask;
            float m2 = acc[q][2] * vmask, m3 = acc[q][3] * vmask;
            float sp = sgn4[q][0] * m0 + sgn4[q][1] * m1
                     + sgn4[q][2] * m2 + sgn4[q][3] * m3;
            float sq = m0 * m0 + m1 * m1 + m2 * m2 + m3 * m3;
#pragma unroll
            for (int o = 1; o < 16; o <<= 1) {
                sp += __shfl_xor(sp, o, 64);
                sq += __shfl_xor(sq, o, 64);
            }
            sA[q] += sp; ssA[q] += sq;
        }
    }

    // ---- combine partial stats deterministically ----
    if (p15 == 0) {
#pragma unroll
        for (int q = 0; q < 4; q++) {
            gsum[wave][q * 4 + lg][0] = sA[q];
            gsum[wave][q * 4 + lg][1] = ssA[q];
        }
    }
    __syncthreads();
    if (tid < 32) {
        int g = tid >> 1, which = tid & 1;
        float v = gsum[0][g][which] + gsum[1][g][which]
                + gsum[2][g][which] + gsum[3][g][which];
        ws[((size_t)(n * NBAND + band) * NG + g) * 2 + which] = v;
    }
}

// PHASE 2: in-place affine + clamp over out (raw pooled signed-max).
// mean/rstd from the 4 band-partials per (n,g). Proven R9 pattern.
__launch_bounds__(256)
__global__ void finalize_phase2(const float* __restrict__ gn_w,
                                const float* __restrict__ gn_b,
                                const float* __restrict__ scale,
                                const float* __restrict__ ws,
                                float* __restrict__ out) {
    const int total = N_IMG * OC * PH * PW;
    const float inv_count = 1.f / (float)(4 * 126 * 126);
    int stride = gridDim.x * 256;
    for (int i = blockIdx.x * 256 + threadIdx.x; i < total; i += stride) {
        int n = i / (OC * PH * PW);
        int rem = i - n * (OC * PH * PW);
        int c = rem / (PH * PW);
        int g = c >> 2;
        float S = 0.f, SS = 0.f;
#pragma unroll
        for (int bnd = 0; bnd < NBAND; bnd++) {
            size_t wb = ((size_t)(n * NBAND + bnd) * NG + g) * 2;
            S += ws[wb];
            SS += ws[wb + 1];
        }
        float mean = S * inv_count;
        float var = SS * inv_count - mean * mean;
        if (var < 0.f) var = 0.f;
        float rstd = rsqrtf(var + GN_EPS);
        float gw = gn_w[c], sc = scale[c];
        float a2 = rstd * fabsf(gw * sc);
        float b2 = (gn_b[c] - mean * rstd * gw) * sc;
        float v = fmaf(a2, out[i], b2);
        out[i] = fminf(fmaxf(v, 0.f), 1.f);
    }
}

extern "C" void kernel_launch(void* const* d_in, const int* in_sizes, int n_in,
                              void* d_out, int out_size, void* d_ws, size_t ws_size,
                              hipStream_t stream) {
    const float* x      = (const float*)d_in[0];
    const float* conv_w = (const float*)d_in[1];
    const float* conv_b = (const float*)d_in[2];
    const float* gn_w   = (const float*)d_in[3];
    const float* gn_b   = (const float*)d_in[4];
    const float* scale  = (const float*)d_in[5];
    float* out = (float*)d_out;
    float* ws  = (float*)d_ws;   // 512 * 16 * 2 floats = 64 KB

    hipLaunchKernelGGL(conv_pool_mfma_phase1, dim3(N_IMG * NBAND), dim3(256),
                       0, stream, x, conv_w, conv_b, gn_w, gn_b, scale, out, ws);
    hipLaunchKernelGGL(finalize_phase2, dim3(2048), dim3(256), 0, stream,
                       gn_w, gn_b, scale, ws, out);
}